// Round 6
// baseline (648.878 us; speedup 1.0000x reference)
//
#include <hip/hip_runtime.h>
#include <math.h>

#define NN 8192
#define FF 64
#define ALPHA 0.2f
#define ECAP 512   // k_e per-wave nz-list capacity (row mean 164, max ~230)
#define WCAP 256   // k_att per-wave segment capacity (mean 41, max ~90)

typedef float vf4 __attribute__((ext_vector_type(4)));  // clang vector: ok for nontemporal builtins

// ---------------- Kernel 1: h_att = h @ W ----------------
__global__ __launch_bounds__(256) void k_hatt(const float* __restrict__ h,
                                              const float* __restrict__ W,
                                              float* __restrict__ h_att) {
    __shared__ float Ws[64 * 64];
    int t = threadIdx.x;
    for (int k = t; k < 64 * 64; k += 256) Ws[k] = W[k];
    __syncthreads();
    int idx = blockIdx.x * 256 + t;
    int r = idx >> 6, c = idx & 63;
    const float* hr = h + (size_t)r * FF;
    float acc = 0.f;
#pragma unroll
    for (int k = 0; k < 64; ++k) acc += hr[k] * Ws[k * 64 + c];
    h_att[idx] = acc;
}

// ---------------- Kernel 2: e[i] — wave per row, ballot compaction ----------------
__global__ __launch_bounds__(256) void k_e(const float* __restrict__ node_adj,
                                           const float* __restrict__ h_att,
                                           const float* __restrict__ a,
                                           float* __restrict__ e) {
    __shared__ int lists[4][ECAP];
    int t = threadIdx.x, w = t >> 6, lane = t & 63;
    int row = blockIdx.x * 4 + w;
    unsigned long long lmask = (1ull << lane) - 1ull;
    const vf4* rp = (const vf4*)(node_adj + (size_t)row * NN);
    int cnt = 0;
#pragma unroll 4
    for (int it = 0; it < 32; ++it) {
        int idx = it * 64 + lane;
        vf4 v = __builtin_nontemporal_load(rp + idx);
        int j0 = idx * 4;
        { bool nz = v.x != 0.f; unsigned long long m = __ballot(nz);
          if (nz) lists[w][cnt + __popcll(m & lmask)] = (v.x > 0.f) ? (j0 + 1) : -(j0 + 1);
          cnt += __popcll(m); }
        { bool nz = v.y != 0.f; unsigned long long m = __ballot(nz);
          if (nz) lists[w][cnt + __popcll(m & lmask)] = (v.y > 0.f) ? (j0 + 2) : -(j0 + 2);
          cnt += __popcll(m); }
        { bool nz = v.z != 0.f; unsigned long long m = __ballot(nz);
          if (nz) lists[w][cnt + __popcll(m & lmask)] = (v.z > 0.f) ? (j0 + 3) : -(j0 + 3);
          cnt += __popcll(m); }
        { bool nz = v.w != 0.f; unsigned long long m = __ballot(nz);
          if (nz) lists[w][cnt + __popcll(m & lmask)] = (v.w > 0.f) ? (j0 + 4) : -(j0 + 4);
          cnt += __popcll(m); }
    }
    __syncthreads();

    float acc = 0.f;   // lane = feature
    for (int k = 0; k < cnt; ++k) {
        int code = lists[w][k];
        int j = (code < 0 ? -code : code) - 1;
        float hv = h_att[(size_t)j * FF + lane];
        acc += (code < 0) ? -hv : hv;
    }
    float v = fabsf(acc) * a[lane];
#pragma unroll
    for (int off = 32; off; off >>= 1) v += __shfl_down(v, off, 64);
    if (lane == 0) e[row] = (v > 0.f) ? v : ALPHA * v;
}

// ---------------- Kernel 2b: E[j] = exp(e[j] - max(e)) ----------------
__global__ __launch_bounds__(256) void k_prep(const float* __restrict__ e,
                                              float* __restrict__ E) {
    __shared__ float red[256];
    int t = threadIdx.x;
    float lm = -3.0e38f;
    for (int k = t; k < NN; k += 256) lm = fmaxf(lm, e[k]);
    red[t] = lm; __syncthreads();
    for (int s = 128; s; s >>= 1) { if (t < s) red[t] = fmaxf(red[t], red[t + s]); __syncthreads(); }
    float m = red[0];
    int i = blockIdx.x * 256 + t;
    E[i] = __expf(e[i] - m);
}

// ---------------- Kernel 3: attention row + h_prime ----------------
// Scan keeps only a 32-bit nz bitmask per thread (no o[8] staging); the dense
// write re-reads E (L2-hot) and reconstructs the row from the bitmask.
__global__ __launch_bounds__(256) void k_att(const float* __restrict__ edge_adj,
                                             const float* __restrict__ E,
                                             const float* __restrict__ h,
                                             float* __restrict__ att_out,
                                             float* __restrict__ hprime) {
    __shared__ int   jseg[4][WCAP];
    __shared__ float vseg[4][WCAP];
    __shared__ float red[256];
    __shared__ float r4z[4];
    __shared__ int   cnts[4];
    int t = threadIdx.x, w = t >> 6, lane = t & 63;
    int row = blockIdx.x;
    unsigned long long lmask = (1ull << lane) - 1ull;

    const vf4* rp = (const vf4*)(edge_adj + (size_t)row * NN);
    const vf4* Ep = (const vf4*)E;
    unsigned int nzbits = 0;
    float zloc = 0.f;
    int cnt = 0;
#pragma unroll
    for (int it = 0; it < 8; ++it) {
        int idx = it * 256 + t;
        vf4 v  = __builtin_nontemporal_load(rp + idx);
        vf4 Ev = Ep[idx];
        int j0 = idx * 4;
        { bool nz = v.x != 0.f; unsigned long long m = __ballot(nz);
          if (nz) { int p = cnt + __popcll(m & lmask); jseg[w][p] = j0;     vseg[w][p] = v.x * Ev.x; }
          cnt += __popcll(m); zloc += nz ? Ev.x : 0.f; nzbits |= (nz ? 1u : 0u) << (it * 4 + 0); }
        { bool nz = v.y != 0.f; unsigned long long m = __ballot(nz);
          if (nz) { int p = cnt + __popcll(m & lmask); jseg[w][p] = j0 + 1; vseg[w][p] = v.y * Ev.y; }
          cnt += __popcll(m); zloc += nz ? Ev.y : 0.f; nzbits |= (nz ? 1u : 0u) << (it * 4 + 1); }
        { bool nz = v.z != 0.f; unsigned long long m = __ballot(nz);
          if (nz) { int p = cnt + __popcll(m & lmask); jseg[w][p] = j0 + 2; vseg[w][p] = v.z * Ev.z; }
          cnt += __popcll(m); zloc += nz ? Ev.z : 0.f; nzbits |= (nz ? 1u : 0u) << (it * 4 + 2); }
        { bool nz = v.w != 0.f; unsigned long long m = __ballot(nz);
          if (nz) { int p = cnt + __popcll(m & lmask); jseg[w][p] = j0 + 3; vseg[w][p] = v.w * Ev.w; }
          cnt += __popcll(m); zloc += nz ? Ev.w : 0.f; nzbits |= (nz ? 1u : 0u) << (it * 4 + 3); }
    }
    if (lane == 0) cnts[w] = cnt;
#pragma unroll
    for (int off = 32; off; off >>= 1) zloc += __shfl_down(zloc, off, 64);
    if (lane == 0) r4z[w] = zloc;
    __syncthreads();
    float Z = r4z[0] + r4z[1] + r4z[2] + r4z[3];
    int tot = cnts[0] + cnts[1] + cnts[2] + cnts[3];
    float invZ = (tot > 0) ? 1.f / Z : 0.f;

    // ---- h_prime gather: lane = feature, each wave walks its own segment ----
    float acc = 0.f;
    for (int k = 0; k < cnt; ++k)
        acc += vseg[w][k] * h[(size_t)jseg[w][k] * FF + lane];
    red[t] = acc;
    __syncthreads();
    if (t < 64)
        hprime[(size_t)row * FF + t] = (red[t] + red[t + 64] + red[t + 128] + red[t + 192]) * invZ;

    // ---- dense coalesced write: reconstruct from bitmask + L2-hot E re-read ----
    vf4* ap = (vf4*)(att_out + (size_t)row * NN);
    float unif = 1.0f / NN;
#pragma unroll
    for (int it = 0; it < 8; ++it) {
        int idx = it * 256 + t;
        vf4 Ev = Ep[idx];
        unsigned b = (nzbits >> (it * 4)) & 15u;
        vf4 ov;
        ov.x = (b & 1u) ? Ev.x * invZ : 0.f;
        ov.y = (b & 2u) ? Ev.y * invZ : 0.f;
        ov.z = (b & 4u) ? Ev.z * invZ : 0.f;
        ov.w = (b & 8u) ? Ev.w * invZ : 0.f;
        if (tot == 0) { ov.x = unif; ov.y = unif; ov.z = unif; ov.w = unif; }
        __builtin_nontemporal_store(ov, ap + idx);
    }
}

extern "C" void kernel_launch(void* const* d_in, const int* in_sizes, int n_in,
                              void* d_out, int out_size, void* d_ws, size_t ws_size,
                              hipStream_t stream) {
    const float* h        = (const float*)d_in[0];
    const float* node_adj = (const float*)d_in[1];
    const float* edge_adj = (const float*)d_in[2];
    const float* W_att    = (const float*)d_in[3];
    const float* a        = (const float*)d_in[4];

    float* out    = (float*)d_out;
    float* hprime = out;                               // [8192, 64]
    float* att    = out + (size_t)NN * FF;             // [8192, 8192]

    float* h_att = (float*)d_ws;                       // [8192, 64]
    float* e_vec = h_att + (size_t)NN * FF;            // [8192]
    float* E_vec = e_vec + NN;                         // [8192]

    k_hatt<<<(NN * FF) / 256, 256, 0, stream>>>(h, W_att, h_att);
    k_e<<<NN / 4, 256, 0, stream>>>(node_adj, h_att, a, e_vec);
    k_prep<<<NN / 256, 256, 0, stream>>>(e_vec, E_vec);
    k_att<<<NN, 256, 0, stream>>>(edge_adj, E_vec, h, att, hprime);
}

// Round 7
// 626.280 us; speedup vs baseline: 1.0361x; 1.0361x over previous
//
#include <hip/hip_runtime.h>
#include <math.h>

#define NN 8192
#define FF 64
#define ALPHA 0.2f
#define ECAP 512   // k_e per-wave nz-list capacity (row mean 164, max ~230)
#define WCAP 256   // k_att per-wave segment capacity (mean 41, max ~90)

typedef float vf4 __attribute__((ext_vector_type(4)));  // clang vector: ok for nontemporal builtins

// ---------------- Kernel 1: h_att = h @ W ----------------
__global__ __launch_bounds__(256) void k_hatt(const float* __restrict__ h,
                                              const float* __restrict__ W,
                                              float* __restrict__ h_att) {
    __shared__ float Ws[64 * 64];
    int t = threadIdx.x;
    for (int k = t; k < 64 * 64; k += 256) Ws[k] = W[k];
    __syncthreads();
    int idx = blockIdx.x * 256 + t;
    int r = idx >> 6, c = idx & 63;
    const float* hr = h + (size_t)r * FF;
    float acc = 0.f;
#pragma unroll
    for (int k = 0; k < 64; ++k) acc += hr[k] * Ws[k * 64 + c];
    h_att[idx] = acc;
}

// ---------------- Kernel 2: e[i] — wave per row, ballot compaction ----------------
__global__ __launch_bounds__(256) void k_e(const float* __restrict__ node_adj,
                                           const float* __restrict__ h_att,
                                           const float* __restrict__ a,
                                           float* __restrict__ e) {
    __shared__ int lists[4][ECAP];
    int t = threadIdx.x, w = t >> 6, lane = t & 63;
    int row = blockIdx.x * 4 + w;
    unsigned long long lmask = (1ull << lane) - 1ull;
    const vf4* rp = (const vf4*)(node_adj + (size_t)row * NN);
    int cnt = 0;
#pragma unroll 4
    for (int it = 0; it < 32; ++it) {
        int idx = it * 64 + lane;
        vf4 v = __builtin_nontemporal_load(rp + idx);
        int j0 = idx * 4;
        { bool nz = v.x != 0.f; unsigned long long m = __ballot(nz);
          if (nz) lists[w][cnt + __popcll(m & lmask)] = (v.x > 0.f) ? (j0 + 1) : -(j0 + 1);
          cnt += __popcll(m); }
        { bool nz = v.y != 0.f; unsigned long long m = __ballot(nz);
          if (nz) lists[w][cnt + __popcll(m & lmask)] = (v.y > 0.f) ? (j0 + 2) : -(j0 + 2);
          cnt += __popcll(m); }
        { bool nz = v.z != 0.f; unsigned long long m = __ballot(nz);
          if (nz) lists[w][cnt + __popcll(m & lmask)] = (v.z > 0.f) ? (j0 + 3) : -(j0 + 3);
          cnt += __popcll(m); }
        { bool nz = v.w != 0.f; unsigned long long m = __ballot(nz);
          if (nz) lists[w][cnt + __popcll(m & lmask)] = (v.w > 0.f) ? (j0 + 4) : -(j0 + 4);
          cnt += __popcll(m); }
    }
    __syncthreads();

    float acc = 0.f;   // lane = feature
    for (int k = 0; k < cnt; ++k) {
        int code = lists[w][k];
        int j = (code < 0 ? -code : code) - 1;
        float hv = h_att[(size_t)j * FF + lane];
        acc += (code < 0) ? -hv : hv;
    }
    float v = fabsf(acc) * a[lane];
#pragma unroll
    for (int off = 32; off; off >>= 1) v += __shfl_down(v, off, 64);
    if (lane == 0) e[row] = (v > 0.f) ? v : ALPHA * v;
}

// ---------------- Kernel 2b: E[j] = exp(e[j] - max(e)) ----------------
__global__ __launch_bounds__(256) void k_prep(const float* __restrict__ e,
                                              float* __restrict__ E) {
    __shared__ float red[256];
    int t = threadIdx.x;
    float lm = -3.0e38f;
    for (int k = t; k < NN; k += 256) lm = fmaxf(lm, e[k]);
    red[t] = lm; __syncthreads();
    for (int s = 128; s; s >>= 1) { if (t < s) red[t] = fmaxf(red[t], red[t + s]); __syncthreads(); }
    float m = red[0];
    int i = blockIdx.x * 256 + t;
    E[i] = __expf(e[i] - m);
}

// ---------------- Kernel 3: attention row + h_prime ----------------
// o[8] register staging of the output row (measured best: r4 = 630 µs vs
// r6 bitmask+E-reread = 649 µs — the E re-read costs L2 BW, registers are free).
__global__ __launch_bounds__(256) void k_att(const float* __restrict__ edge_adj,
                                             const float* __restrict__ E,
                                             const float* __restrict__ h,
                                             float* __restrict__ att_out,
                                             float* __restrict__ hprime) {
    __shared__ int   jseg[4][WCAP];
    __shared__ float vseg[4][WCAP];
    __shared__ float red[256];
    __shared__ float r4z[4];
    __shared__ int   cnts[4];
    int t = threadIdx.x, w = t >> 6, lane = t & 63;
    int row = blockIdx.x;
    unsigned long long lmask = (1ull << lane) - 1ull;

    const vf4* rp = (const vf4*)(edge_adj + (size_t)row * NN);
    const vf4* Ep = (const vf4*)E;
    vf4 o[8];
    float zloc = 0.f;
    int cnt = 0;
#pragma unroll
    for (int it = 0; it < 8; ++it) {
        int idx = it * 256 + t;
        vf4 v  = __builtin_nontemporal_load(rp + idx);
        vf4 Ev = Ep[idx];
        int j0 = idx * 4;
        { bool nz = v.x != 0.f; unsigned long long m = __ballot(nz);
          float ox = nz ? Ev.x : 0.f;
          if (nz) { int p = cnt + __popcll(m & lmask); jseg[w][p] = j0;     vseg[w][p] = v.x * Ev.x; }
          cnt += __popcll(m); zloc += ox; o[it].x = ox; }
        { bool nz = v.y != 0.f; unsigned long long m = __ballot(nz);
          float oy = nz ? Ev.y : 0.f;
          if (nz) { int p = cnt + __popcll(m & lmask); jseg[w][p] = j0 + 1; vseg[w][p] = v.y * Ev.y; }
          cnt += __popcll(m); zloc += oy; o[it].y = oy; }
        { bool nz = v.z != 0.f; unsigned long long m = __ballot(nz);
          float oz = nz ? Ev.z : 0.f;
          if (nz) { int p = cnt + __popcll(m & lmask); jseg[w][p] = j0 + 2; vseg[w][p] = v.z * Ev.z; }
          cnt += __popcll(m); zloc += oz; o[it].z = oz; }
        { bool nz = v.w != 0.f; unsigned long long m = __ballot(nz);
          float ow = nz ? Ev.w : 0.f;
          if (nz) { int p = cnt + __popcll(m & lmask); jseg[w][p] = j0 + 3; vseg[w][p] = v.w * Ev.w; }
          cnt += __popcll(m); zloc += ow; o[it].w = ow; }
    }
    if (lane == 0) cnts[w] = cnt;
#pragma unroll
    for (int off = 32; off; off >>= 1) zloc += __shfl_down(zloc, off, 64);
    if (lane == 0) r4z[w] = zloc;
    __syncthreads();
    float Z = r4z[0] + r4z[1] + r4z[2] + r4z[3];
    int tot = cnts[0] + cnts[1] + cnts[2] + cnts[3];
    float invZ = (tot > 0) ? 1.f / Z : 0.f;

    // ---- h_prime gather: lane = feature, each wave walks its own segment ----
    float acc = 0.f;
    for (int k = 0; k < cnt; ++k)
        acc += vseg[w][k] * h[(size_t)jseg[w][k] * FF + lane];
    red[t] = acc;
    __syncthreads();
    if (t < 64)
        hprime[(size_t)row * FF + t] = (red[t] + red[t + 64] + red[t + 128] + red[t + 192]) * invZ;

    // ---- dense coalesced write ----
    vf4* ap = (vf4*)(att_out + (size_t)row * NN);
    float unif = 1.0f / NN;
#pragma unroll
    for (int it = 0; it < 8; ++it) {
        int idx = it * 256 + t;
        vf4 ov = o[it];
        ov.x *= invZ; ov.y *= invZ; ov.z *= invZ; ov.w *= invZ;
        if (tot == 0) { ov.x = unif; ov.y = unif; ov.z = unif; ov.w = unif; }
        __builtin_nontemporal_store(ov, ap + idx);
    }
}

extern "C" void kernel_launch(void* const* d_in, const int* in_sizes, int n_in,
                              void* d_out, int out_size, void* d_ws, size_t ws_size,
                              hipStream_t stream) {
    const float* h        = (const float*)d_in[0];
    const float* node_adj = (const float*)d_in[1];
    const float* edge_adj = (const float*)d_in[2];
    const float* W_att    = (const float*)d_in[3];
    const float* a        = (const float*)d_in[4];

    float* out    = (float*)d_out;
    float* hprime = out;                               // [8192, 64]
    float* att    = out + (size_t)NN * FF;             // [8192, 8192]

    float* h_att = (float*)d_ws;                       // [8192, 64]
    float* e_vec = h_att + (size_t)NN * FF;            // [8192]
    float* E_vec = e_vec + NN;                         // [8192]

    k_hatt<<<(NN * FF) / 256, 256, 0, stream>>>(h, W_att, h_att);
    k_e<<<NN / 4, 256, 0, stream>>>(node_adj, h_att, a, e_vec);
    k_prep<<<NN / 256, 256, 0, stream>>>(e_vec, E_vec);
    k_att<<<NN, 256, 0, stream>>>(edge_adj, E_vec, h, att, hprime);
}